// Round 5
// baseline (231.308 us; speedup 1.0000x reference)
//
#include <hip/hip_runtime.h>
#include <math.h>

#define NIMG 32
#define NB3  771             // 257 rings * 3 sums
#define PI_F 3.14159265358979323846f

// ---------------------------------------------------------------------------
__device__ __forceinline__ float2 cadd(float2 a, float2 b){ return make_float2(a.x+b.x, a.y+b.y); }
__device__ __forceinline__ float2 csub(float2 a, float2 b){ return make_float2(a.x-b.x, a.y-b.y); }
__device__ __forceinline__ float2 cmul(float2 a, float2 b){ return make_float2(a.x*b.x - a.y*b.y, a.x*b.y + a.y*b.x); }
__device__ __forceinline__ float2 cmul_mi(float2 a){ return make_float2(a.y, -a.x); }   // * (-i)
__device__ __forceinline__ float2 tw(const float2* T, int m){ return T[m + (m >> 3)]; }

// 8-point DFT (DIF, natural-order outputs), e^{-2pi i/8} convention
__device__ __forceinline__ void dft8(float2* x) {
    const float c = 0.70710678118654752f;
    float2 u0 = cadd(x[0], x[4]), u1 = cadd(x[1], x[5]);
    float2 u2 = cadd(x[2], x[6]), u3 = cadd(x[3], x[7]);
    float2 v0 = csub(x[0], x[4]);
    float2 d1 = csub(x[1], x[5]);
    float2 v1 = make_float2(c*(d1.x + d1.y), c*(d1.y - d1.x));
    float2 d2 = csub(x[2], x[6]);
    float2 v2 = make_float2(d2.y, -d2.x);
    float2 d3 = csub(x[3], x[7]);
    float2 v3 = make_float2(-c*(d3.x - d3.y), -c*(d3.x + d3.y));
    float2 e0 = cadd(u0,u2), e1 = cadd(u1,u3);
    float2 f0 = csub(u0,u2), f1 = cmul_mi(csub(u1,u3));
    float2 g0 = cadd(v0,v2), g1 = cadd(v1,v3);
    float2 h0 = csub(v0,v2), h1 = cmul_mi(csub(v1,v3));
    x[0] = cadd(e0,e1); x[4] = csub(e0,e1);
    x[2] = cadd(f0,f1); x[6] = csub(f0,f1);
    x[1] = cadd(g0,g1); x[5] = csub(g0,g1);
    x[3] = cadd(h0,h1); x[7] = csub(h0,h1);
}

// ---------------------------------------------------------------------------
// Dual per-wave 512-pt radix-8 DIF FFT, NO barriers (wave-private LDS regions;
// LDS ops from one wave execute in order). Thread J enters with
// X[q] = x[J + 64q], exits with X[k] = F(64k + r), r = 8*(J&7) + (J>>3).
// S0/S1: two 576-float2 scratch regions (pad-per-8 swizzle).
// ---------------------------------------------------------------------------
__device__ __forceinline__ void wave_fft512_dual(float2* X0, float2* X1,
                                                 float2* S0, float2* S1,
                                                 const float2* T, int J) {
    float2 W[8];
    dft8(X0); dft8(X1);
#pragma unroll
    for (int k = 1; k < 8; ++k) W[k] = tw(T, J * k);
#pragma unroll
    for (int k = 1; k < 8; ++k) { X0[k] = cmul(X0[k], W[k]); X1[k] = cmul(X1[k], W[k]); }
    const int jj = J + (J >> 3);
#pragma unroll
    for (int k = 0; k < 8; ++k) { S0[jj + 72*k] = X0[k]; S1[jj + 72*k] = X1[k]; }

    const int j2 = J & 7;
    const int bb = 72 * (J >> 3) + j2;
#pragma unroll
    for (int q = 0; q < 8; ++q) { X0[q] = S0[bb + 9*q]; X1[q] = S1[bb + 9*q]; }
    dft8(X0); dft8(X1);
#pragma unroll
    for (int k = 1; k < 8; ++k) W[k] = tw(T, 8 * j2 * k);
#pragma unroll
    for (int k = 1; k < 8; ++k) { X0[k] = cmul(X0[k], W[k]); X1[k] = cmul(X1[k], W[k]); }
#pragma unroll
    for (int k = 0; k < 8; ++k) { S0[bb + 9*k] = X0[k]; S1[bb + 9*k] = X1[k]; }

#pragma unroll
    for (int q = 0; q < 8; ++q) { X0[q] = S0[9*J + q]; X1[q] = S1[9*J + q]; }
    dft8(X0); dft8(X1);
}

// ---------------------------------------------------------------------------
// Row pass: 256 threads = 4 waves; wave w does rows grp*8+w and grp*8+w+4.
// Output transposed Zt[kx][y] via aliased LDS transpose, 64B/thread stores.
// ---------------------------------------------------------------------------
__global__ __launch_bounds__(256, 3) void fft_rows_T(const float* __restrict__ xr,
                                                     const float* __restrict__ yr,
                                                     float2* __restrict__ Zt) {
    __shared__ float2 S[8 * 576];   // 36,864 B: FFT scratch, then transpose buffer (aliased)
    __shared__ float2 T[576];
    const int t = threadIdx.x, w = t >> 6, J = t & 63;
    const int im = blockIdx.x >> 6, grp = blockIdx.x & 63;

#pragma unroll
    for (int i = 0; i < 2; ++i) {
        const int m = t + 256 * i;
        float sw, cw;
        __sincosf(-2.0f * PI_F * (float)m / 512.0f, &sw, &cw);
        T[m + (m >> 3)] = make_float2(cw, sw);
    }

    const size_t b0 = ((size_t)(im * 512 + grp * 8 + w)) << 9;
    const size_t b1 = b0 + (4u << 9);
    float2 X0[8], X1[8];
#pragma unroll
    for (int q = 0; q < 8; ++q) {
        X0[q] = make_float2(xr[b0 + J + 64*q], yr[b0 + J + 64*q]);
        X1[q] = make_float2(xr[b1 + J + 64*q], yr[b1 + J + 64*q]);
    }
    __syncthreads();                          // T ready

    wave_fft512_dual(X0, X1, S + (2*w) * 576, S + (2*w + 1) * 576, T, J);
    __syncthreads();                          // all stage-3 reads done; S becomes transpose buf

    const int r = ((J & 7) << 3) | (J >> 3);
#pragma unroll
    for (int k = 0; k < 8; ++k) {
        S[576*k + 9*r + w]     = X0[k];       // y-local = w
        S[576*k + 9*r + w + 4] = X1[k];       // y-local = w+4
    }
    __syncthreads();

#pragma unroll
    for (int half = 0; half < 2; ++half) {
        const int kx = t + 256 * half;
        const int base = 576 * (kx >> 6) + 9 * (kx & 63);
        float4* o4 = (float4*)(Zt + ((size_t)im << 18) + ((size_t)kx << 9) + (grp << 3));
#pragma unroll
        for (int i = 0; i < 4; ++i) {
            float2 e0 = S[base + 2*i];
            float2 e1 = S[base + 2*i + 1];
            o4[i] = make_float4(e0.x, e0.y, e1.x, e1.y);
        }
    }
}

// ---------------------------------------------------------------------------
// Column pass + fused rings. Wave w owns a mirror column pair:
//   g=0 : w0:(0,256) [self-mirrors], w1:(1,511), w2:(2,510), w3:(3,509)
//   g>0 : (4g+w, 512-(4g+w))
// After FFT, un-digit-reversed natural-ky data in wave regions; ring phase
// reads conjugate partners cross-wave, deposits via HW LDS float atomics
// into parity-split bins; flush = plain stores to a private slice (big path).
// ---------------------------------------------------------------------------
__global__ __launch_bounds__(256, 3) void fft_cols_rings(const float2* __restrict__ Zt,
                                                         float* __restrict__ sums,
                                                         int big) {
    __shared__ float2 S[8 * 576];      // 36,864 B
    __shared__ float2 T[576];          //  4,608 B
    __shared__ float  bins[2][774];    //  6,192 B (parity-split, ring 257 = discard)
    const int t = threadIdx.x, w = t >> 6, J = t & 63;
    const int im = blockIdx.x >> 6, g = blockIdx.x & 63;

#pragma unroll
    for (int i = 0; i < 2; ++i) {
        const int m = t + 256 * i;
        float sw, cw;
        __sincosf(-2.0f * PI_F * (float)m / 512.0f, &sw, &cw);
        T[m + (m >> 3)] = make_float2(cw, sw);
    }
    for (int i = t; i < 2 * 774; i += 256) bins[0][i] = 0.0f;   // flat fill both copies

    int c0, c1;
    if (g == 0) { c0 = (w == 0) ? 0 : w; c1 = (w == 0) ? 256 : 512 - w; }
    else        { c0 = 4 * g + w;        c1 = 512 - c0; }

    const float2* rp0 = Zt + ((size_t)im << 18) + ((size_t)c0 << 9);
    const float2* rp1 = Zt + ((size_t)im << 18) + ((size_t)c1 << 9);
    float2 X0[8], X1[8];
#pragma unroll
    for (int q = 0; q < 8; ++q) { X0[q] = rp0[J + 64*q]; X1[q] = rp1[J + 64*q]; }
    __syncthreads();                          // T ready

    float2* S0 = S + (2*w) * 576;
    float2* S1 = S + (2*w + 1) * 576;
    wave_fft512_dual(X0, X1, S0, S1, T, J);

    // un-digit-reverse into own regions, natural ky (same wave: in-order, no barrier)
    const int r = ((J & 7) << 3) | (J >> 3);
#pragma unroll
    for (int k = 0; k < 8; ++k) { S0[64*k + r] = X0[k]; S1[64*k + r] = X1[k]; }
    __syncthreads();                          // natural-order data visible to all waves

    const float scale = 1.0f / (512.0f * 512.0f);
    float* bp = bins[t & 1];

    auto pix = [&](float2 zk, float2 zm, float& av, float& c1v, float& c2v) {
        float f1r = 0.5f * (zk.x + zm.x) * scale;
        float f1i = 0.5f * (zk.y - zm.y) * scale;
        float f2r = 0.5f * (zk.y + zm.y) * scale;
        float f2i = 0.5f * (zm.x - zk.x) * scale;
        av  = f1r * f2r + f1i * f2i;
        c1v = f1r * f1r + f1i * f1i;
        c2v = f2r * f2r + f2i * f2i;
    };

#pragma unroll
    for (int half = 0; half < 2; ++half) {
        const int ky  = t + 256 * half;
        const int kyp = (512 - ky) & 511;
        const float fxv = (ky < 256) ? (float)ky : (float)(ky - 512);
        const float fx2 = fxv * fxv;
#pragma unroll
        for (int u = 0; u < 4; ++u) {
            const float2* A = S + (2*u) * 576;
            const float2* B = S + (2*u + 1) * 576;
            float2 zka = A[ky], zma = A[kyp];
            float2 zkb = B[ky], zmb = B[kyp];
            if (g == 0 && u == 0) {
                // col 0 and col 256 are each self-mirror: two separate rings
                float av, c1v, c2v;
                pix(zka, zma, av, c1v, c2v);
                int rr = (int)rintf(sqrtf(fx2));
                if (rr > 256) rr = 257;
                unsafeAtomicAdd(&bp[rr*3+0], av);
                unsafeAtomicAdd(&bp[rr*3+1], c1v);
                unsafeAtomicAdd(&bp[rr*3+2], c2v);
                pix(zkb, zmb, av, c1v, c2v);
                rr = (int)rintf(sqrtf(fx2 + 65536.0f));
                if (rr > 256) rr = 257;
                unsafeAtomicAdd(&bp[rr*3+0], av);
                unsafeAtomicAdd(&bp[rr*3+1], c1v);
                unsafeAtomicAdd(&bp[rr*3+2], c2v);
            } else {
                const float fy = (float)((g == 0) ? u : 4*g + u);
                float a1, b1, d1, a2, b2, d2;
                pix(zka, zmb, a1, b1, d1);     // (ky, c0): partner (-ky, c1)
                pix(zkb, zma, a2, b2, d2);     // (ky, c1): partner (-ky, c0)
                int rr = (int)rintf(sqrtf(fx2 + fy * fy));
                if (rr > 256) rr = 257;
                unsafeAtomicAdd(&bp[rr*3+0], a1 + a2);
                unsafeAtomicAdd(&bp[rr*3+1], b1 + b2);
                unsafeAtomicAdd(&bp[rr*3+2], d1 + d2);
            }
        }
    }
    __syncthreads();

    if (big) {
        float* dst = sums + (size_t)blockIdx.x * NB3;          // private slice
        for (int i = t; i < NB3; i += 256) dst[i] = bins[0][i] + bins[1][i];
    } else {
        float* dst = sums + (size_t)(im * 8 + (g & 7)) * NB3;  // shared slice
        for (int i = t; i < NB3; i += 256) unsafeAtomicAdd(&dst[i], bins[0][i] + bins[1][i]);
    }
}

// ---------------------------------------------------------------------------
// Finalize: block = image; sum slices per ring; mean of (1-frc)^2.
// C_i ring sums are exactly 0 by k -> -k antisymmetry; dropped.
// ---------------------------------------------------------------------------
__global__ __launch_bounds__(256) void finalize(const float* __restrict__ sums,
                                                float* __restrict__ out, int spi) {
    const int b = blockIdx.x, t = threadIdx.x;
    float acc = 0.0f;
    for (int r = t; r < 257; r += 256) {
        float cr = 0.f, c1 = 0.f, c2 = 0.f;
        for (int s = 0; s < spi; ++s) {
            const float* p = sums + (size_t)(b * spi + s) * NB3 + r * 3;
            cr += p[0]; c1 += p[1]; c2 += p[2];
        }
        float frc = fabsf(cr) / (sqrtf(c1 * c2) + 1e-8f);
        float d = 1.0f - frc;
        acc += d * d;
    }
#pragma unroll
    for (int off = 32; off > 0; off >>= 1) acc += __shfl_down(acc, off);
    __shared__ float red[4];
    if ((t & 63) == 0) red[t >> 6] = acc;
    __syncthreads();
    if (t == 0)
        unsafeAtomicAdd(out, (red[0] + red[1] + red[2] + red[3]) *
                             (1.0f / (257.0f * (float)NIMG)));
}

// ---------------------------------------------------------------------------
extern "C" void kernel_launch(void* const* d_in, const int* in_sizes, int n_in,
                              void* d_out, int out_size, void* d_ws, size_t ws_size,
                              hipStream_t stream) {
    const float* xr = (const float*)d_in[0];   // output: 32x1x512x512 f32
    const float* yr = (const float*)d_in[1];   // target: 32x1x512x512 f32

    float2* Zt = (float2*)d_ws;                                    // 64 MiB
    const size_t ztBytes = ((size_t)NIMG << 18) * sizeof(float2);
    float* sums = (float*)((char*)d_ws + ztBytes);
    const int big = (ws_size >= ztBytes + (size_t)2048 * NB3 * sizeof(float)) ? 1 : 0;

    if (!big)
        hipMemsetAsync(sums, 0, (size_t)NIMG * 8 * NB3 * sizeof(float), stream);
    hipMemsetAsync(d_out, 0, sizeof(float), stream);

    fft_rows_T    <<<dim3(NIMG * 64), dim3(256), 0, stream>>>(xr, yr, Zt);
    fft_cols_rings<<<dim3(NIMG * 64), dim3(256), 0, stream>>>(Zt, sums, big);
    finalize      <<<dim3(NIMG), dim3(256), 0, stream>>>(sums, (float*)d_out, big ? 64 : 8);
}